// Round 2
// 431.353 us; speedup vs baseline: 1.2777x; 1.2777x over previous
//
#include <hip/hip_runtime.h>

// CostVolume: out[b,h,w,i0*9+j0] = mean_c( prv[b,h,w,c] * nxt[b,h+i0-4,w+j0-4,c] )
// B=16, H=W=128, C=192, r=4, d=9, 81 offsets. fp32 in/out, bf16 MFMA internally.
//
// v2 (resubmit; previous round was a container-acquisition failure, not a kernel
// verdict): 4-wave (256-thread) blocks on an 8x8 prv tile. The shared 16x16 nxt
// halo is staged per-32-channel chunk into LDS as bf16, double-buffered, with
// coalesced batched global loads (8 dwordx4 in flight -> one waitcnt). Each wave
// computes its 4x4 quadrant's 16x144 Gram with mfma_f32_16x16x32_bf16, A-fragments
// (prv) held in registers. Rationale: v1 was load-latency serialized (120 scattered
// gathers x ~1.1k cyc ~= measured 137k cyc/block; MfmaUtil 2%, HBM 25%, occ 37%).
// LDS: 2 x 20480 staging buffers, reused for epilogue G (39168 B) -> 40960 B total
// = exactly 4 blocks/CU (16 waves/CU).

typedef __attribute__((ext_vector_type(8))) short short8;
typedef __attribute__((ext_vector_type(4))) float float4v;
typedef __attribute__((ext_vector_type(2))) unsigned int uint2v;

#define HH 128
#define WW 128
#define CC 192
#define PSTRIDE 80                 // LDS bytes per halo pixel (64 B data + 16 B pad)
#define BUFB (256 * PSTRIDE)       // 20480 B per staging buffer
#define GROWP 17                   // G leading-dim stride in floats (odd -> bank-spread)
#define GWAVE (144 * GROWP)        // 2448 floats per wave's G region

// packed f32x2 -> bf16x2 (RNE). Non-volatile: let the scheduler move/CSE it.
static __device__ __forceinline__ unsigned int pk2(float lo, float hi) {
    unsigned int r;
    asm("v_cvt_pk_bf16_f32 %0, %1, %2" : "=v"(r) : "v"(lo), "v"(hi));
    return r;
}

// 8 contiguous fp32 -> bf16 MFMA fragment
static __device__ __forceinline__ short8 cvt8pk(const float* __restrict__ p) {
    float4v f0 = *reinterpret_cast<const float4v*>(p);
    float4v f1 = *reinterpret_cast<const float4v*>(p + 4);
    union { unsigned int u[4]; short8 s; } r;
    r.u[0] = pk2(f0[0], f0[1]);
    r.u[1] = pk2(f0[2], f0[3]);
    r.u[2] = pk2(f1[0], f1[1]);
    r.u[3] = pk2(f1[2], f1[3]);
    return r.s;
}

__global__ __launch_bounds__(256, 4) void costvol_kernel(
    const float* __restrict__ prv,
    const float* __restrict__ nxt,
    float* __restrict__ out)
{
    const int tid  = threadIdx.x;        // 0..255
    const int lane = tid & 63;
    const int wv   = tid >> 6;           // wave 0..3
    const int m    = lane & 15;
    const int q    = lane >> 4;
    const int wr   = wv >> 1, wc = wv & 1;   // quadrant (row, col) in 8x8 tile

    const int wt = blockIdx.x, ht = blockIdx.y, b = blockIdx.z;
    const int h0 = ht * 8, w0 = wt * 8;

    const float* nxt_b = nxt + (size_t)b * HH * WW * CC;
    const float* prv_b = prv + (size_t)b * HH * WW * CC;

    __shared__ alignas(16) unsigned char smem[2 * BUFB];

    // ---- staging geometry: thread -> (halo pixel column, 16B part) ----
    // P = i*32 + u32 covers all 256 halo pixels over i=0..7.
    const int u32 = tid >> 3;            // 0..31
    const int j   = tid & 7;             // 16B part within a pixel's 32-ch chunk
    const int hc  = u32 & 15;            // halo col 0..15
    const int d   = u32 >> 4;            // row parity
    const int wwg = w0 - 4 + hc;         // global col of this thread's halo column
    const bool okw = (wwg >= 0) && (wwg < WW);
    const int wcl = wwg < 0 ? 0 : (wwg > WW - 1 ? WW - 1 : wwg);

    int stage_off[8];                    // clamped element offsets into nxt_b
    unsigned okmask = 0;
#pragma unroll
    for (int i = 0; i < 8; ++i) {
        int hh = h0 - 4 + 2 * i + d;     // global row, covers all 16 halo rows
        bool ok = okw && (hh >= 0) && (hh < HH);
        int hcl = hh < 0 ? 0 : (hh > HH - 1 ? HH - 1 : hh);
        stage_off[i] = (hcl * WW + wcl) * CC + j * 4;
        okmask |= (unsigned)ok << i;
    }
    const int wbase = u32 * PSTRIDE + j * 8;   // LDS write byte base (b64 aligned)

    // ---- B-fragment LDS read offsets (per lane, per displacement set s) ----
    int roff[9];
#pragma unroll
    for (int s = 0; s < 9; ++s) {
        int n  = s * 16 + m;             // quadrant-halo index in 12x12
        int nr = n / 12, nc = n - nr * 12;
        int P  = (wr * 4 + nr) * 16 + (wc * 4 + nc);  // 16x16 halo pixel
        roff[s] = P * PSTRIDE + q * 16;  // 16B aligned -> ds_read_b128
    }

    // ---- prv A-fragments: load once into registers ----
    const int pr = m >> 2, pc = m & 3;
    const float* pbase =
        prv_b + ((size_t)(h0 + wr * 4 + pr) * WW + (w0 + wc * 4 + pc)) * CC + q * 8;
    short8 afrag[6];
#pragma unroll
    for (int kk = 0; kk < 6; ++kk) afrag[kk] = cvt8pk(pbase + kk * 32);

    // ---- prologue: stage chunk 0 into buf0 ----
    {
        float4v sv[8];
#pragma unroll
        for (int i = 0; i < 8; ++i)
            sv[i] = *reinterpret_cast<const float4v*>(nxt_b + stage_off[i]);
#pragma unroll
        for (int i = 0; i < 8; ++i) {
            uint2v p;
            p.x = pk2(sv[i][0], sv[i][1]);
            p.y = pk2(sv[i][2], sv[i][3]);
            if (!((okmask >> i) & 1u)) { p.x = 0u; p.y = 0u; }
            *reinterpret_cast<uint2v*>(&smem[i * (32 * PSTRIDE) + wbase]) = p;
        }
    }
    __syncthreads();

    float4v acc[9];
#pragma unroll
    for (int s = 0; s < 9; ++s) acc[s] = (float4v){0.f, 0.f, 0.f, 0.f};

    // ---- main K loop: 6 chunks of 32 channels, double-buffered staging ----
#pragma unroll
    for (int kk = 0; kk < 6; ++kk) {
        float4v sv[8];
        if (kk < 5) {                    // issue next chunk's loads (stay in flight)
#pragma unroll
            for (int i = 0; i < 8; ++i)
                sv[i] = *reinterpret_cast<const float4v*>(
                    nxt_b + stage_off[i] + (kk + 1) * 32);
        }
        // compute on buf[kk&1]
        const int rb = (kk & 1) * BUFB;
        short8 a = afrag[kk];
#pragma unroll
        for (int s = 0; s < 9; ++s) {
            short8 bf = *reinterpret_cast<const short8*>(&smem[rb + roff[s]]);
            acc[s] = __builtin_amdgcn_mfma_f32_16x16x32_bf16(a, bf, acc[s], 0, 0, 0);
        }
        if (kk < 5) {                    // convert + write next chunk into other buf
            const int wb = ((kk + 1) & 1) * BUFB;
#pragma unroll
            for (int i = 0; i < 8; ++i) {
                uint2v p;
                p.x = pk2(sv[i][0], sv[i][1]);
                p.y = pk2(sv[i][2], sv[i][3]);
                if (!((okmask >> i) & 1u)) { p.x = 0u; p.y = 0u; }
                *reinterpret_cast<uint2v*>(&smem[wb + i * (32 * PSTRIDE) + wbase]) = p;
            }
        }
        __syncthreads();
    }

    // ---- epilogue: G through LDS (reuses staging space), coalesced stores ----
    // lane (q,m), set s holds D[prv=q*4+r][halo n=s*16+m] for its quadrant.
    float* Gf = reinterpret_cast<float*>(smem);
    const int gbase = wv * GWAVE;
#pragma unroll
    for (int s = 0; s < 9; ++s) {
        int col = s * 16 + m;
#pragma unroll
        for (int r = 0; r < 4; ++r)
            Gf[gbase + col * GROWP + q * 4 + r] = acc[s][r];
    }
    __syncthreads();

    const float scale = 1.0f / 192.0f;
    // 8x8 px * 81 offsets = 5184 floats, flat-indexed; rows of 648 floats contiguous.
#pragma unroll
    for (int t = 0; t < 21; ++t) {
        int f = t * 256 + tid;
        if (f < 5184) {
            int p   = f / 81;            // tile pixel 0..63
            int k   = f - p * 81;        // offset 0..80
            int i0  = k / 9, j0 = k - i0 * 9;
            int pr8 = p >> 3, pc8 = p & 7;
            int gw  = ((pr8 >> 2) << 1) | (pc8 >> 2);        // owning wave
            int pi  = ((pr8 & 3) << 2) | (pc8 & 3);          // pixel within quadrant
            int col = ((pr8 & 3) + i0) * 12 + ((pc8 & 3) + j0);
            float v = Gf[gw * GWAVE + col * GROWP + pi] * scale;
            out[((size_t)(b * HH + (h0 + pr8)) * WW + (w0 + pc8)) * 81 + k] = v;
        }
    }
}

extern "C" void kernel_launch(void* const* d_in, const int* in_sizes, int n_in,
                              void* d_out, int out_size, void* d_ws, size_t ws_size,
                              hipStream_t stream) {
    const float* prv = (const float*)d_in[0];
    const float* nxt = (const float*)d_in[1];
    float* out = (float*)d_out;
    dim3 grid(WW / 8, HH / 8, 16);   // w-tiles, h-tiles, batch
    dim3 block(256);
    hipLaunchKernelGGL(costvol_kernel, grid, block, 0, stream, prv, nxt, out);
}